// Round 1
// baseline (746.701 us; speedup 1.0000x reference)
//
#include <hip/hip_runtime.h>

// LinearCrossAttention: B=8, N=T=4096, C=512, H=8, d=64, 3 terms.
// All heavy GEMMs in bf16 MFMA (16x16x32), f32 accumulation.

#define B_  8
#define N_  4096
#define C_  512
#define T_  4096
#define H_  8
#define D_  64
#define M_  (B_*N_)   // 32768

typedef __bf16 bf16_8 __attribute__((ext_vector_type(8)));
typedef float  f32_4  __attribute__((ext_vector_type(4)));

__device__ __forceinline__ unsigned short f2bf(float f) {
  unsigned u = __float_as_uint(f);
  unsigned r = 0x7FFFu + ((u >> 16) & 1u);
  return (unsigned short)((u + r) >> 16);
}
__device__ __forceinline__ float bf2f(unsigned short h) {
  return __uint_as_float(((unsigned)h) << 16);
}

__device__ __forceinline__ void gload16(const void* g, void* l) {
  __builtin_amdgcn_global_load_lds(
      (const __attribute__((address_space(1))) unsigned int*)g,
      (__attribute__((address_space(3))) unsigned int*)l, 16, 0, 0);
}

// ---------------- f32 -> bf16 conversion (4 elems/thread/iter) --------------
__global__ __launch_bounds__(256) void cvt_f32_bf16(
    const float* __restrict__ in, unsigned short* __restrict__ out, long n4)
{
  long i = (long)blockIdx.x * blockDim.x + threadIdx.x;
  long stride = (long)gridDim.x * blockDim.x;
  for (; i < n4; i += stride) {
    float4 v = ((const float4*)in)[i];
    ushort4 o;
    o.x = f2bf(v.x); o.y = f2bf(v.y); o.z = f2bf(v.z); o.w = f2bf(v.w);
    ((ushort4*)out)[i] = o;
  }
}

// ---------------- GEMM: C[m,n] = sum_k A[m,k]*W[n,k] + bias[n] --------------
// m97-style: 128x128 tile, BK=64, 4 waves, 4x4 16x16x32 frags, global_load_lds
template<int STOREF32>
__global__ __launch_bounds__(256) void gemm_bt(
    const unsigned short* __restrict__ A,   // M x K bf16
    const unsigned short* __restrict__ Bw,  // N x K bf16 (weight rows = out cols)
    const float* __restrict__ bias,         // N
    float* __restrict__ Cf, unsigned short* __restrict__ Cb,
    int M, int N, int K)
{
  __shared__ unsigned short sA[128*64];
  __shared__ unsigned short sB[128*64];
  const int tid  = threadIdx.x;
  const int lane = tid & 63;
  const int wid  = tid >> 6;
  const int wr = wid >> 1, wc = wid & 1;
  const int l15 = lane & 15, l16 = lane >> 4;
  const size_t row0 = (size_t)blockIdx.x * 128;
  const size_t col0 = (size_t)blockIdx.y * 128;

  f32_4 acc[4][4] = {};

  for (int k0 = 0; k0 < K; k0 += 64) {
#pragma unroll
    for (int j = 0; j < 4; ++j) {
      int c = j*256 + tid;            // 16B chunk id, 0..1023
      int row = c >> 3, c8 = c & 7;
      // per-lane global src, wave-uniform LDS base (+lane*16 in HW)
      gload16(A  + (row0 + row)*(size_t)K + k0 + c8*8, sA + (size_t)(j*256 + wid*64)*8);
      gload16(Bw + (col0 + row)*(size_t)K + k0 + c8*8, sB + (size_t)(j*256 + wid*64)*8);
    }
    __syncthreads();
#pragma unroll
    for (int kk = 0; kk < 64; kk += 32) {
      bf16_8 af[4], bf[4];
#pragma unroll
      for (int mi = 0; mi < 4; ++mi)
        af[mi] = *(const bf16_8*)&sA[(wr*64 + mi*16 + l15)*64 + kk + l16*8];
#pragma unroll
      for (int ni = 0; ni < 4; ++ni)
        bf[ni] = *(const bf16_8*)&sB[(wc*64 + ni*16 + l15)*64 + kk + l16*8];
#pragma unroll
      for (int mi = 0; mi < 4; ++mi)
#pragma unroll
        for (int ni = 0; ni < 4; ++ni)
          acc[mi][ni] = __builtin_amdgcn_mfma_f32_16x16x32_bf16(af[mi], bf[ni], acc[mi][ni], 0, 0, 0);
    }
    __syncthreads();
  }

#pragma unroll
  for (int mi = 0; mi < 4; ++mi) {
    int rb = wr*64 + mi*16 + l16*4;
#pragma unroll
    for (int ni = 0; ni < 4; ++ni) {
      int col = wc*64 + ni*16 + l15;
      float bv = bias[col0 + col];
#pragma unroll
      for (int jj = 0; jj < 4; ++jj) {
        size_t idx = (row0 + rb + jj)*(size_t)N + col0 + col;
        float val = acc[mi][ni][jj] + bv;
        if constexpr (STOREF32) Cf[idx] = val;
        else                    Cb[idx] = f2bf(val);
      }
    }
  }
}

// ---------------- softmax over contiguous 64-elem segments ------------------
__global__ __launch_bounds__(256) void softmax64(
    const float* __restrict__ pre, unsigned short* __restrict__ out)
{
  size_t seg = (size_t)blockIdx.x * 4 + (threadIdx.x >> 6);
  int lane = threadIdx.x & 63;
  size_t idx = seg * 64 + lane;
  float x = pre[idx];
  float m = x;
#pragma unroll
  for (int o = 32; o; o >>= 1) m = fmaxf(m, __shfl_xor(m, o));
  float e = __expf(x - m);
  float s = e;
#pragma unroll
  for (int o = 32; o; o >>= 1) s += __shfl_xor(s, o);
  out[idx] = f2bf(e / s);
}

// ---------------- ctx[b,h] += k^T v (64x64, K=T), kc[b,h,d] += sum_t k ------
__global__ __launch_bounds__(256) void ctx_kernel(
    const unsigned short* __restrict__ k, const unsigned short* __restrict__ v,
    float* __restrict__ ctx,   // [64bh][64][64]
    float* __restrict__ kc)    // [64bh][64]
{
  __shared__ unsigned short kT[64*136];  // transposed [d][t], +8 pad
  __shared__ unsigned short vT[64*136];
  const int tid = threadIdx.x;
  const int lane = tid & 63, wid = tid >> 6;
  const int wr = wid >> 1, wc = wid & 1;
  const int l15 = lane & 15, l16 = lane >> 4;
  const int bh = blockIdx.y, b = bh >> 3, h = bh & 7;
  const int t0 = blockIdx.x * 512;

  f32_4 acc[2][2] = {};
  float kcacc = 0.f;
  const int kcd = tid & 63, kcq = tid >> 6;

  for (int tt = 0; tt < 4; ++tt) {
    const size_t gbase = ((size_t)b*T_ + t0 + tt*128)*C_ + h*64;
#pragma unroll
    for (int it = 0; it < 8; ++it) {
      int c = it*256 + tid;            // 0..2047 (first 1024 = k, rest = v)
      int c2 = c & 1023;
      int t = c2 >> 3, d0 = (c2 & 7)*8;
      const unsigned short* src = ((c < 1024) ? k : v) + gbase + (size_t)t*C_ + d0;
      unsigned short* dst = (c < 1024) ? kT : vT;
      uint4 w = *(const uint4*)src;
      dst[(d0+0)*136 + t] = (unsigned short)(w.x & 0xffff);
      dst[(d0+1)*136 + t] = (unsigned short)(w.x >> 16);
      dst[(d0+2)*136 + t] = (unsigned short)(w.y & 0xffff);
      dst[(d0+3)*136 + t] = (unsigned short)(w.y >> 16);
      dst[(d0+4)*136 + t] = (unsigned short)(w.z & 0xffff);
      dst[(d0+5)*136 + t] = (unsigned short)(w.z >> 16);
      dst[(d0+6)*136 + t] = (unsigned short)(w.w & 0xffff);
      dst[(d0+7)*136 + t] = (unsigned short)(w.w >> 16);
    }
    __syncthreads();
    // kc partials (sum over t of softmaxed k)
#pragma unroll
    for (int s = 0; s < 32; ++s)
      kcacc += bf2f(kT[kcd*136 + kcq*32 + s]);
    // MFMA: each wave a 32x32 quadrant, K=128 in 4 substeps
#pragma unroll
    for (int ks = 0; ks < 4; ++ks) {
      bf16_8 af[2], bfr[2];
#pragma unroll
      for (int mi = 0; mi < 2; ++mi)
        af[mi] = *(const bf16_8*)&kT[(wr*32 + mi*16 + l15)*136 + ks*32 + l16*8];
#pragma unroll
      for (int ni = 0; ni < 2; ++ni)
        bfr[ni] = *(const bf16_8*)&vT[(wc*32 + ni*16 + l15)*136 + ks*32 + l16*8];
#pragma unroll
      for (int mi = 0; mi < 2; ++mi)
#pragma unroll
        for (int ni = 0; ni < 2; ++ni)
          acc[mi][ni] = __builtin_amdgcn_mfma_f32_16x16x32_bf16(af[mi], bfr[ni], acc[mi][ni], 0, 0, 0);
    }
    __syncthreads();
  }

  float* cbase = ctx + (size_t)bh * 64*64;
#pragma unroll
  for (int mi = 0; mi < 2; ++mi)
#pragma unroll
    for (int ni = 0; ni < 2; ++ni)
#pragma unroll
      for (int jj = 0; jj < 4; ++jj) {
        int dk = wr*32 + mi*16 + l16*4 + jj;
        int dv = wc*32 + ni*16 + l15;
        atomicAdd(cbase + dk*64 + dv, acc[mi][ni][jj]);
      }
  atomicAdd(kc + (size_t)bh*64 + kcd, kcacc * 0.25f * 0.0f + kcacc); // plain add
}

// ---------------- combine: out_pre = q + sum_i (q @ ctx_i) / (q . kc_i) -----
__global__ __launch_bounds__(256) void combine_kernel(
    const unsigned short* __restrict__ q,   // (B,N,C) bf16
    const float* __restrict__ ctx,          // [3][64bh][64][64]
    const float* __restrict__ kc,           // [3][64bh][64]
    unsigned short* __restrict__ outp)      // (B,N,C) bf16
{
  __shared__ unsigned short a_t[128*200];   // A' = [q/s1,q/s2,q/s3], K=192, +8 pad
  __shared__ unsigned short b_t[64*200];    // stacked ctx^T: [dv][i*64+e]
  const int tid = threadIdx.x, lane = tid & 63, wid = tid >> 6;
  const int l15 = lane & 15, l16 = lane >> 4;
  const int bh = blockIdx.y, b = bh >> 3, h = bh & 7;
  const int n0 = blockIdx.x * 128;

  for (int it = 0; it < 48; ++it) {
    int flat = it*256 + tid;       // 0..12287
    int i  = flat >> 12;
    int e  = (flat >> 6) & 63;
    int dv = flat & 63;
    float val = ctx[(((size_t)i*64 + bh)*64 + e)*64 + dv];
    b_t[dv*200 + i*64 + e] = f2bf(val);
  }
  float kcv[3];
#pragma unroll
  for (int i = 0; i < 3; ++i) kcv[i] = kc[((size_t)i*64 + bh)*64 + lane];

  const size_t qbase = ((size_t)b*N_ + n0)*C_ + h*64;
  for (int r = wid*32; r < wid*32 + 32; ++r) {
    float qv = bf2f(q[qbase + (size_t)r*C_ + lane]);
    float sinv[3];
#pragma unroll
    for (int i = 0; i < 3; ++i) {
      float p = qv * kcv[i];
#pragma unroll
      for (int o = 32; o; o >>= 1) p += __shfl_xor(p, o);
      sinv[i] = 1.0f / p;
    }
#pragma unroll
    for (int i = 0; i < 3; ++i)
      a_t[r*200 + i*64 + lane] = f2bf(qv * sinv[i]);
  }
  __syncthreads();

  f32_4 acc[2][4] = {};
#pragma unroll
  for (int ks = 0; ks < 6; ++ks) {
    bf16_8 af[2], bfr[4];
#pragma unroll
    for (int mi = 0; mi < 2; ++mi)
      af[mi] = *(const bf16_8*)&a_t[(wid*32 + mi*16 + l15)*200 + ks*32 + l16*8];
#pragma unroll
    for (int ni = 0; ni < 4; ++ni)
      bfr[ni] = *(const bf16_8*)&b_t[(ni*16 + l15)*200 + ks*32 + l16*8];
#pragma unroll
    for (int mi = 0; mi < 2; ++mi)
#pragma unroll
      for (int ni = 0; ni < 4; ++ni)
        acc[mi][ni] = __builtin_amdgcn_mfma_f32_16x16x32_bf16(af[mi], bfr[ni], acc[mi][ni], 0, 0, 0);
  }

#pragma unroll
  for (int mi = 0; mi < 2; ++mi)
#pragma unroll
    for (int ni = 0; ni < 4; ++ni)
#pragma unroll
      for (int jj = 0; jj < 4; ++jj) {
        int r = wid*32 + mi*16 + l16*4 + jj;
        int c = ni*16 + l15;
        size_t gi = qbase + (size_t)r*C_ + c;
        outp[gi] = f2bf(bf2f(q[gi]) + acc[mi][ni][jj]);
      }
}

// ---------------------------------------------------------------------------
extern "C" void kernel_launch(void* const* d_in, const int* in_sizes, int n_in,
                              void* d_out, int out_size, void* d_ws, size_t ws_size,
                              hipStream_t stream)
{
  const float* x  = (const float*)d_in[0];
  const float* y  = (const float*)d_in[1];
  const float* Wq = (const float*)d_in[2];
  const float* bq = (const float*)d_in[3];
  const float* Wk = (const float*)d_in[4];
  const float* bk = (const float*)d_in[5];
  const float* Wv = (const float*)d_in[6];
  const float* bv = (const float*)d_in[7];
  const float* Wp = (const float*)d_in[8];
  const float* bp = (const float*)d_in[9];
  float* out = (float*)d_out;
  char* ws = (char*)d_ws;

  const size_t SZ_PRE = (size_t)M_ * C_ * 4;  // 64 MB f32 scratch (pre-softmax)
  const size_t SZ_BF  = (size_t)M_ * C_ * 2;  // 32 MB bf16

  float*          pre  = (float*)(ws);
  unsigned short* srcb = (unsigned short*)(ws + SZ_PRE);
  unsigned short* qb   = (unsigned short*)(ws + SZ_PRE + 1*SZ_BF);
  unsigned short* kb   = (unsigned short*)(ws + SZ_PRE + 2*SZ_BF);  // also out_pre
  unsigned short* vb   = (unsigned short*)(ws + SZ_PRE + 3*SZ_BF);
  unsigned short* wb   = (unsigned short*)(ws + SZ_PRE + 4*SZ_BF);  // 8*C*C bf16
  float* ctx = (float*)(ws + SZ_PRE + 4*SZ_BF + (size_t)8*C_*C_*2);
  float* kc  = ctx + (size_t)3*64*64*64;

  unsigned short* wq_b = wb;
  unsigned short* wk_b = wb + (size_t)1*C_*C_;
  unsigned short* wv_b = wb + (size_t)4*C_*C_;
  unsigned short* wp_b = wb + (size_t)7*C_*C_;

  // conversions f32 -> bf16
  cvt_f32_bf16<<<2048, 256, 0, stream>>>(x,  srcb, (long)M_*C_/4);
  cvt_f32_bf16<<<256,  256, 0, stream>>>(Wq, wq_b, (long)C_*C_/4);
  cvt_f32_bf16<<<256,  256, 0, stream>>>(Wk, wk_b, (long)3*C_*C_/4);
  cvt_f32_bf16<<<256,  256, 0, stream>>>(Wv, wv_b, (long)3*C_*C_/4);
  cvt_f32_bf16<<<256,  256, 0, stream>>>(Wp, wp_b, (long)C_*C_/4);

  dim3 gg(M_/128, C_/128);
  // q = softmax(x @ Wq^T + bq)
  gemm_bt<1><<<gg, 256, 0, stream>>>(srcb, wq_b, bq, pre, nullptr, M_, C_, C_);
  softmax64<<<(M_*H_)/4, 256, 0, stream>>>(pre, qb);

  hipMemsetAsync(ctx, 0, ((size_t)3*64*64*64 + (size_t)3*64*64) * sizeof(float), stream);

  for (int i = 0; i < 3; ++i) {
    cvt_f32_bf16<<<2048, 256, 0, stream>>>(y + (size_t)i*M_*C_, srcb, (long)M_*C_/4);
    gemm_bt<1><<<gg, 256, 0, stream>>>(srcb, wk_b + (size_t)i*C_*C_, bk + i*C_, pre, nullptr, M_, C_, C_);
    softmax64<<<(M_*H_)/4, 256, 0, stream>>>(pre, kb);
    gemm_bt<0><<<gg, 256, 0, stream>>>(srcb, wv_b + (size_t)i*C_*C_, bv + i*C_, nullptr, vb, M_, C_, C_);
    ctx_kernel<<<dim3(8, 64), 256, 0, stream>>>(kb, vb,
        ctx + (size_t)i*64*64*64, kc + (size_t)i*64*64);
  }

  combine_kernel<<<dim3(32, 64), 256, 0, stream>>>(qb, ctx, kc, kb);
  gemm_bt<1><<<gg, 256, 0, stream>>>(kb, wp_b, bp, out, nullptr, M_, C_, C_);
}

// Round 3
// 696.198 us; speedup vs baseline: 1.0725x; 1.0725x over previous
//
#include <hip/hip_runtime.h>

// LinearCrossAttention: B=8, N=T=4096, C=512, H=8, d=64, 3 terms.
// R3: R2 design with combine2 q-staging bug fixed (1024 chunks, row=c>>3).

#define B_  8
#define N_  4096
#define C_  512
#define T_  4096
#define H_  8
#define M_  (B_*N_)   // 32768

typedef __bf16 bf16_8 __attribute__((ext_vector_type(8)));
typedef float  f32_4  __attribute__((ext_vector_type(4)));

__device__ __forceinline__ unsigned short f2bf(float f) {
  unsigned u = __float_as_uint(f);
  unsigned r = 0x7FFFu + ((u >> 16) & 1u);
  return (unsigned short)((u + r) >> 16);
}
__device__ __forceinline__ float bf2f(unsigned short h) {
  return __uint_as_float(((unsigned)h) << 16);
}

__device__ __forceinline__ void gload16(const void* g, void* l) {
  __builtin_amdgcn_global_load_lds(
      (const __attribute__((address_space(1))) unsigned int*)g,
      (__attribute__((address_space(3))) unsigned int*)l, 16, 0, 0);
}

// ---------------- f32 -> bf16 conversion ------------------------------------
__global__ __launch_bounds__(256) void cvt_f32_bf16(
    const float* __restrict__ in, unsigned short* __restrict__ out, long n4)
{
  long i = (long)blockIdx.x * blockDim.x + threadIdx.x;
  long stride = (long)gridDim.x * blockDim.x;
  for (; i < n4; i += stride) {
    float4 v = ((const float4*)in)[i];
    ushort4 o;
    o.x = f2bf(v.x); o.y = f2bf(v.y); o.z = f2bf(v.z); o.w = f2bf(v.w);
    ((ushort4*)out)[i] = o;
  }
}

// ---------------- plain GEMM (f32 out + bias): final projection -------------
__global__ __launch_bounds__(256) void gemm_f32(
    const unsigned short* __restrict__ A,   // M x 512 bf16
    const unsigned short* __restrict__ Bw,  // 512 x 512 bf16 (W rows = out cols)
    const float* __restrict__ bias,
    float* __restrict__ Cf)
{
  __shared__ unsigned short sA[128*64];
  __shared__ unsigned short sB[128*64];
  const int tid  = threadIdx.x;
  const int lane = tid & 63, wid = tid >> 6;
  const int wr = wid >> 1, wc = wid & 1;
  const int l15 = lane & 15, l16 = lane >> 4;
  const size_t row0 = (size_t)blockIdx.x * 128;
  const size_t col0 = (size_t)blockIdx.y * 128;

  f32_4 acc[4][4] = {};
  for (int k0 = 0; k0 < C_; k0 += 64) {
#pragma unroll
    for (int j = 0; j < 4; ++j) {
      int c = j*256 + tid;
      int row = c >> 3, c8 = c & 7;
      gload16(A  + (row0 + row)*(size_t)C_ + k0 + c8*8, sA + (size_t)(j*256 + wid*64)*8);
      gload16(Bw + (col0 + row)*(size_t)C_ + k0 + c8*8, sB + (size_t)(j*256 + wid*64)*8);
    }
    __syncthreads();
#pragma unroll
    for (int kk = 0; kk < 64; kk += 32) {
      bf16_8 af[4], bfr[4];
#pragma unroll
      for (int mi = 0; mi < 4; ++mi)
        af[mi] = *(const bf16_8*)&sA[(wr*64 + mi*16 + l15)*64 + kk + l16*8];
#pragma unroll
      for (int ni = 0; ni < 4; ++ni)
        bfr[ni] = *(const bf16_8*)&sB[(wc*64 + ni*16 + l15)*64 + kk + l16*8];
#pragma unroll
      for (int mi = 0; mi < 4; ++mi)
#pragma unroll
        for (int ni = 0; ni < 4; ++ni)
          acc[mi][ni] = __builtin_amdgcn_mfma_f32_16x16x32_bf16(af[mi], bfr[ni], acc[mi][ni], 0, 0, 0);
    }
    __syncthreads();
  }
#pragma unroll
  for (int mi = 0; mi < 4; ++mi) {
    int rb = wr*64 + mi*16 + l16*4;
#pragma unroll
    for (int ni = 0; ni < 4; ++ni) {
      int col = wc*64 + ni*16 + l15;
      float bv = bias[col0 + col];
#pragma unroll
      for (int jj = 0; jj < 4; ++jj)
        Cf[(row0 + rb + jj)*(size_t)C_ + col0 + col] = acc[mi][ni][jj] + bv;
    }
  }
}

// ---------------- GEMM + fused per-64-col softmax (q path) ------------------
__global__ __launch_bounds__(256) void gemm_sm(
    const unsigned short* __restrict__ A,
    const unsigned short* __restrict__ Bw,
    const float* __restrict__ bias,
    unsigned short* __restrict__ Cb)
{
  __shared__ unsigned short sA[128*64];
  __shared__ unsigned short sB[128*64];
  const int tid  = threadIdx.x;
  const int lane = tid & 63, wid = tid >> 6;
  const int wr = wid >> 1, wc = wid & 1;
  const int l15 = lane & 15, l16 = lane >> 4;
  const size_t row0 = (size_t)blockIdx.x * 128;
  const size_t col0 = (size_t)blockIdx.y * 128;

  f32_4 acc[4][4] = {};
  for (int k0 = 0; k0 < C_; k0 += 64) {
#pragma unroll
    for (int j = 0; j < 4; ++j) {
      int c = j*256 + tid;
      int row = c >> 3, c8 = c & 7;
      gload16(A  + (row0 + row)*(size_t)C_ + k0 + c8*8, sA + (size_t)(j*256 + wid*64)*8);
      gload16(Bw + (col0 + row)*(size_t)C_ + k0 + c8*8, sB + (size_t)(j*256 + wid*64)*8);
    }
    __syncthreads();
#pragma unroll
    for (int kk = 0; kk < 64; kk += 32) {
      bf16_8 af[4], bfr[4];
#pragma unroll
      for (int mi = 0; mi < 4; ++mi)
        af[mi] = *(const bf16_8*)&sA[(wr*64 + mi*16 + l15)*64 + kk + l16*8];
#pragma unroll
      for (int ni = 0; ni < 4; ++ni)
        bfr[ni] = *(const bf16_8*)&sB[(wc*64 + ni*16 + l15)*64 + kk + l16*8];
#pragma unroll
      for (int mi = 0; mi < 4; ++mi)
#pragma unroll
        for (int ni = 0; ni < 4; ++ni)
          acc[mi][ni] = __builtin_amdgcn_mfma_f32_16x16x32_bf16(af[mi], bfr[ni], acc[mi][ni], 0, 0, 0);
    }
    __syncthreads();
  }

  float bv[4];
#pragma unroll
  for (int ni = 0; ni < 4; ++ni) bv[ni] = bias[col0 + wc*64 + ni*16 + l15];
#pragma unroll
  for (int mi = 0; mi < 4; ++mi) {
#pragma unroll
    for (int jj = 0; jj < 4; ++jj) {
      float x[4];
#pragma unroll
      for (int ni = 0; ni < 4; ++ni) x[ni] = acc[mi][ni][jj] + bv[ni];
      float m = fmaxf(fmaxf(x[0], x[1]), fmaxf(x[2], x[3]));
#pragma unroll
      for (int o = 8; o; o >>= 1) m = fmaxf(m, __shfl_xor(m, o));
      float s = 0.f;
#pragma unroll
      for (int ni = 0; ni < 4; ++ni) { x[ni] = __expf(x[ni] - m); s += x[ni]; }
#pragma unroll
      for (int o = 8; o; o >>= 1) s += __shfl_xor(s, o);
      float inv = 1.0f / s;
      size_t r = row0 + wr*64 + mi*16 + l16*4 + jj;
#pragma unroll
      for (int ni = 0; ni < 4; ++ni)
        Cb[r*(size_t)C_ + col0 + wc*64 + ni*16 + l15] = f2bf(x[ni] * inv);
    }
  }
}

// ---------------- fused K+V GEMM: shared A tile, softmax on K ---------------
__global__ __launch_bounds__(256) void gemm_kv(
    const unsigned short* __restrict__ A,
    const unsigned short* __restrict__ Wk, const float* __restrict__ bk,
    const unsigned short* __restrict__ Wv, const float* __restrict__ bv_,
    unsigned short* __restrict__ Kout, unsigned short* __restrict__ Vout)
{
  __shared__ unsigned short sA[128*64];
  __shared__ unsigned short sK[128*64];
  __shared__ unsigned short sV[128*64];
  const int tid  = threadIdx.x;
  const int lane = tid & 63, wid = tid >> 6;
  const int wr = wid >> 1, wc = wid & 1;
  const int l15 = lane & 15, l16 = lane >> 4;
  const size_t row0 = (size_t)blockIdx.x * 128;
  const size_t col0 = (size_t)blockIdx.y * 128;

  f32_4 accK[4][4] = {}, accV[4][4] = {};
  for (int k0 = 0; k0 < C_; k0 += 64) {
#pragma unroll
    for (int j = 0; j < 4; ++j) {
      int c = j*256 + tid;
      int row = c >> 3, c8 = c & 7;
      size_t lofs = (size_t)(j*256 + wid*64)*8;
      gload16(A  + (row0 + row)*(size_t)C_ + k0 + c8*8, sA + lofs);
      gload16(Wk + (col0 + row)*(size_t)C_ + k0 + c8*8, sK + lofs);
      gload16(Wv + (col0 + row)*(size_t)C_ + k0 + c8*8, sV + lofs);
    }
    __syncthreads();
#pragma unroll
    for (int kk = 0; kk < 64; kk += 32) {
      bf16_8 af[4], kf[4], vf[4];
#pragma unroll
      for (int mi = 0; mi < 4; ++mi)
        af[mi] = *(const bf16_8*)&sA[(wr*64 + mi*16 + l15)*64 + kk + l16*8];
#pragma unroll
      for (int ni = 0; ni < 4; ++ni) {
        kf[ni] = *(const bf16_8*)&sK[(wc*64 + ni*16 + l15)*64 + kk + l16*8];
        vf[ni] = *(const bf16_8*)&sV[(wc*64 + ni*16 + l15)*64 + kk + l16*8];
      }
#pragma unroll
      for (int mi = 0; mi < 4; ++mi)
#pragma unroll
        for (int ni = 0; ni < 4; ++ni) {
          accK[mi][ni] = __builtin_amdgcn_mfma_f32_16x16x32_bf16(af[mi], kf[ni], accK[mi][ni], 0, 0, 0);
          accV[mi][ni] = __builtin_amdgcn_mfma_f32_16x16x32_bf16(af[mi], vf[ni], accV[mi][ni], 0, 0, 0);
        }
    }
    __syncthreads();
  }

  float bkv[4], bvv[4];
#pragma unroll
  for (int ni = 0; ni < 4; ++ni) {
    int col = col0 + wc*64 + ni*16 + l15;
    bkv[ni] = bk[col];
    bvv[ni] = bv_[col];
  }
#pragma unroll
  for (int mi = 0; mi < 4; ++mi) {
#pragma unroll
    for (int jj = 0; jj < 4; ++jj) {
      size_t r = row0 + wr*64 + mi*16 + l16*4 + jj;
      // V: bias + store
#pragma unroll
      for (int ni = 0; ni < 4; ++ni)
        Vout[r*(size_t)C_ + col0 + wc*64 + ni*16 + l15] = f2bf(accV[mi][ni][jj] + bvv[ni]);
      // K: bias + softmax + store
      float x[4];
#pragma unroll
      for (int ni = 0; ni < 4; ++ni) x[ni] = accK[mi][ni][jj] + bkv[ni];
      float m = fmaxf(fmaxf(x[0], x[1]), fmaxf(x[2], x[3]));
#pragma unroll
      for (int o = 8; o; o >>= 1) m = fmaxf(m, __shfl_xor(m, o));
      float s = 0.f;
#pragma unroll
      for (int ni = 0; ni < 4; ++ni) { x[ni] = __expf(x[ni] - m); s += x[ni]; }
#pragma unroll
      for (int o = 8; o; o >>= 1) s += __shfl_xor(s, o);
      float inv = 1.0f / s;
#pragma unroll
      for (int ni = 0; ni < 4; ++ni)
        Kout[r*(size_t)C_ + col0 + wc*64 + ni*16 + l15] = f2bf(x[ni] * inv);
    }
  }
}

// ---------------- ctx: ctxT[bh][dv][e] += sum_t k[t][e]*v[t][dv]; kc += sum_t k
__global__ __launch_bounds__(256) void ctx_kernel(
    const unsigned short* __restrict__ k, const unsigned short* __restrict__ v,
    float* __restrict__ ctxT,  // [64bh][64dv][64e]
    float* __restrict__ kc)    // [64bh][64e]
{
  __shared__ unsigned short kT[64*136];  // transposed [d][t], +8 pad
  __shared__ unsigned short vT[64*136];
  const int tid = threadIdx.x;
  const int lane = tid & 63, wid = tid >> 6;
  const int wr = wid >> 1, wc = wid & 1;
  const int l15 = lane & 15, l16 = lane >> 4;
  const int bh = blockIdx.y, b = bh >> 3, h = bh & 7;
  const int t0 = blockIdx.x * 512;

  f32_4 acc[2][2] = {};
  float kcacc = 0.f;
  const int kcd = tid & 63, kcq = tid >> 6;

  for (int tt = 0; tt < 4; ++tt) {
    const size_t gbase = ((size_t)b*T_ + t0 + tt*128)*C_ + h*64;
#pragma unroll
    for (int it = 0; it < 8; ++it) {
      int c = it*256 + tid;
      int c2 = c & 1023;
      int t = c2 >> 3, d0 = (c2 & 7)*8;
      const unsigned short* src = ((c < 1024) ? k : v) + gbase + (size_t)t*C_ + d0;
      unsigned short* dst = (c < 1024) ? kT : vT;
      uint4 w = *(const uint4*)src;
      dst[(d0+0)*136 + t] = (unsigned short)(w.x & 0xffff);
      dst[(d0+1)*136 + t] = (unsigned short)(w.x >> 16);
      dst[(d0+2)*136 + t] = (unsigned short)(w.y & 0xffff);
      dst[(d0+3)*136 + t] = (unsigned short)(w.y >> 16);
      dst[(d0+4)*136 + t] = (unsigned short)(w.z & 0xffff);
      dst[(d0+5)*136 + t] = (unsigned short)(w.z >> 16);
      dst[(d0+6)*136 + t] = (unsigned short)(w.w & 0xffff);
      dst[(d0+7)*136 + t] = (unsigned short)(w.w >> 16);
    }
    __syncthreads();
#pragma unroll
    for (int s = 0; s < 32; ++s)
      kcacc += bf2f(kT[kcd*136 + kcq*32 + s]);
#pragma unroll
    for (int ks = 0; ks < 4; ++ks) {
      bf16_8 af[2], bfr[2];
#pragma unroll
      for (int mi = 0; mi < 2; ++mi)
        af[mi] = *(const bf16_8*)&kT[(wr*32 + mi*16 + l15)*136 + ks*32 + l16*8];
#pragma unroll
      for (int ni = 0; ni < 2; ++ni)
        bfr[ni] = *(const bf16_8*)&vT[(wc*32 + ni*16 + l15)*136 + ks*32 + l16*8];
#pragma unroll
      for (int mi = 0; mi < 2; ++mi)
#pragma unroll
        for (int ni = 0; ni < 2; ++ni)
          acc[mi][ni] = __builtin_amdgcn_mfma_f32_16x16x32_bf16(af[mi], bfr[ni], acc[mi][ni], 0, 0, 0);
    }
    __syncthreads();
  }

  float* cbase = ctxT + (size_t)bh * 64*64;
#pragma unroll
  for (int mi = 0; mi < 2; ++mi)
#pragma unroll
    for (int ni = 0; ni < 2; ++ni)
#pragma unroll
      for (int jj = 0; jj < 4; ++jj) {
        int dk = wr*32 + mi*16 + l16*4 + jj;   // e index
        int dv = wc*32 + ni*16 + l15;          // v index
        atomicAdd(cbase + dv*64 + dk, acc[mi][ni][jj]);  // TRANSPOSED store
      }
  atomicAdd(kc + (size_t)bh*64 + kcd, kcacc);
}

// ---------------- combine (MFMA): out = q + sum_i (q@ctx_i)/(q.kc_i) --------
__global__ __launch_bounds__(256) void combine2(
    const unsigned short* __restrict__ qb,   // (B,N,C) bf16
    const float* __restrict__ ctxT,          // [3][64bh][64dv][64e]
    const float* __restrict__ kc,            // [3][64bh][64e]
    unsigned short* __restrict__ outp)       // (B,N,C) bf16
{
  __shared__ unsigned short sQ[128*64];      // 16 KB
  __shared__ unsigned short sB[208*64];      // 26 KB : [col][e], cols 0..194 used
  __shared__ float sS[128*3];
  const int tid = threadIdx.x, lane = tid & 63, wid = tid >> 6;
  const int l15 = lane & 15, l16 = lane >> 4;
  const int bh = blockIdx.y, b = bh >> 3, h = bh & 7;
  const int n0 = blockIdx.x * 128;
  const size_t qbase = ((size_t)b*N_ + n0)*C_ + h*64;

  // stage q tile (128x64 bf16 = 1024 x 16B chunks) linear
#pragma unroll
  for (int j = 0; j < 4; ++j) {
    int c = j*256 + tid;              // 0..1023 chunks of 16B
    int row = c >> 3, c8 = c & 7;     // 64 bf16 per row = 8 chunks
    gload16(qb + qbase + (size_t)row*C_ + c8*8, sQ + (size_t)(j*256 + wid*64)*8);
  }
  // fill sB: cols 0..191 = ctxT_i rows, 192..194 = kc_i, rest zero
  for (int f = tid; f < 208*64; f += 256) {
    int col = f >> 6, e = f & 63;
    float val = 0.f;
    if (col < 192)
      val = ctxT[(((size_t)(col >> 6)*64 + bh)*64 + (col & 63))*64 + e];
    else if (col < 195)
      val = kc[((size_t)(col - 192)*64 + bh)*64 + e];
    sB[col*64 + e] = f2bf(val);
  }
  __syncthreads();

  f32_4 acc[2][13] = {};
#pragma unroll
  for (int ks = 0; ks < 2; ++ks) {
    bf16_8 af[2];
#pragma unroll
    for (int mi = 0; mi < 2; ++mi)
      af[mi] = *(const bf16_8*)&sQ[(wid*32 + mi*16 + l15)*64 + ks*32 + l16*8];
#pragma unroll
    for (int ni = 0; ni < 13; ++ni) {
      bf16_8 bfr = *(const bf16_8*)&sB[(ni*16 + l15)*64 + ks*32 + l16*8];
#pragma unroll
      for (int mi = 0; mi < 2; ++mi)
        acc[mi][ni] = __builtin_amdgcn_mfma_f32_16x16x32_bf16(af[mi], bfr, acc[mi][ni], 0, 0, 0);
    }
  }

  // scatter s values (cols 192..194) to LDS
  if (l15 < 3) {
#pragma unroll
    for (int mi = 0; mi < 2; ++mi)
#pragma unroll
      for (int jj = 0; jj < 4; ++jj)
        sS[(wid*32 + mi*16 + l16*4 + jj)*3 + l15] = acc[mi][12][jj];
  }
  __syncthreads();

#pragma unroll
  for (int mi = 0; mi < 2; ++mi) {
#pragma unroll
    for (int jj = 0; jj < 4; ++jj) {
      int r = wid*32 + mi*16 + l16*4 + jj;
      float inv[3];
#pragma unroll
      for (int i = 0; i < 3; ++i) inv[i] = 1.0f / sS[r*3 + i];
#pragma unroll
      for (int ni = 0; ni < 4; ++ni) {
        int dv = ni*16 + l15;
        float val = bf2f(sQ[r*64 + dv]);
#pragma unroll
        for (int i = 0; i < 3; ++i) val += acc[mi][i*4 + ni][jj] * inv[i];
        outp[qbase + (size_t)r*C_ + dv] = f2bf(val);
      }
    }
  }
}

// ---------------------------------------------------------------------------
extern "C" void kernel_launch(void* const* d_in, const int* in_sizes, int n_in,
                              void* d_out, int out_size, void* d_ws, size_t ws_size,
                              hipStream_t stream)
{
  const float* x  = (const float*)d_in[0];
  const float* y  = (const float*)d_in[1];
  const float* Wq = (const float*)d_in[2];
  const float* bq = (const float*)d_in[3];
  const float* Wk = (const float*)d_in[4];
  const float* bk = (const float*)d_in[5];
  const float* Wv = (const float*)d_in[6];
  const float* bv = (const float*)d_in[7];
  const float* Wp = (const float*)d_in[8];
  const float* bp = (const float*)d_in[9];
  float* out = (float*)d_out;
  char* ws = (char*)d_ws;

  const size_t SZ_BF = (size_t)M_ * C_ * 2;  // 32 MB bf16

  unsigned short* srcb = (unsigned short*)(ws);
  unsigned short* qb   = (unsigned short*)(ws + 1*SZ_BF);
  unsigned short* kb   = (unsigned short*)(ws + 2*SZ_BF);  // also out_pre
  unsigned short* vb   = (unsigned short*)(ws + 3*SZ_BF);
  unsigned short* wb   = (unsigned short*)(ws + 4*SZ_BF);  // 8*C*C bf16 = 4MB
  float* ctxT = (float*)(ws + 4*SZ_BF + (size_t)8*C_*C_*2);
  float* kc   = ctxT + (size_t)3*64*64*64;

  unsigned short* wq_b = wb;
  unsigned short* wk_b = wb + (size_t)1*C_*C_;
  unsigned short* wv_b = wb + (size_t)4*C_*C_;
  unsigned short* wp_b = wb + (size_t)7*C_*C_;

  cvt_f32_bf16<<<2048, 256, 0, stream>>>(x,  srcb, (long)M_*C_/4);
  cvt_f32_bf16<<<256,  256, 0, stream>>>(Wq, wq_b, (long)C_*C_/4);
  cvt_f32_bf16<<<256,  256, 0, stream>>>(Wk, wk_b, (long)3*C_*C_/4);
  cvt_f32_bf16<<<256,  256, 0, stream>>>(Wv, wv_b, (long)3*C_*C_/4);
  cvt_f32_bf16<<<256,  256, 0, stream>>>(Wp, wp_b, (long)C_*C_/4);

  hipMemsetAsync(ctxT, 0, ((size_t)3*64*64*64 + (size_t)3*64*64) * sizeof(float), stream);

  dim3 gg(M_/128, C_/128);
  // q = softmax(x @ Wq^T + bq)  (fused)
  gemm_sm<<<gg, 256, 0, stream>>>(srcb, wq_b, bq, qb);

  for (int i = 0; i < 3; ++i) {
    cvt_f32_bf16<<<2048, 256, 0, stream>>>(y + (size_t)i*M_*C_, srcb, (long)M_*C_/4);
    gemm_kv<<<gg, 256, 0, stream>>>(srcb,
        wk_b + (size_t)i*C_*C_, bk + i*C_,
        wv_b + (size_t)i*C_*C_, bv + i*C_,
        kb, vb);
    ctx_kernel<<<dim3(8, 64), 256, 0, stream>>>(kb, vb,
        ctxT + (size_t)i*64*64*64, kc + (size_t)i*64*64);
  }

  combine2<<<dim3(32, 64), 256, 0, stream>>>(qb, ctxT, kc, kb);
  gemm_f32<<<gg, 256, 0, stream>>>(kb, wp_b, bp, out);
}